// Round 2
// baseline (710.390 us; speedup 1.0000x reference)
//
#include <hip/hip_runtime.h>

#define N_IN_CH 256
#define N_OUT_CH 64
#define TILE_R 128
#define KC 64
#define NT_SCAN 1024

// --- Kernel 1: transpose W [64][256] -> WT [256][64] (k-major) ---
__global__ void wt_kernel(const float* __restrict__ W, float* __restrict__ WT) {
    int idx = blockIdx.x * blockDim.x + threadIdx.x;
    if (idx < N_OUT_CH * N_IN_CH) {
        int o = idx >> 8;      // / 256
        int k = idx & 255;
        WT[k * N_OUT_CH + o] = W[idx];
    }
}

// --- Kernel 2: Xp = X @ W^T, fp32, LDS-tiled, 8x4 register tile ---
__global__ __launch_bounds__(256) void gemm_kernel(const float* __restrict__ X,
        const float* __restrict__ WT, float* __restrict__ Xp, int nrows) {
    __shared__ float Xs[TILE_R][KC + 4];   // row-major X chunk, +4 pad (272B stride, 16B-aligned)
    __shared__ float Ws[KC][N_OUT_CH];     // k-major W chunk

    const int tid = threadIdx.x;
    const int row0 = blockIdx.x * TILE_R;
    const int tx = tid & 15;   // channel group: channels tx*4 .. tx*4+3
    const int ty = tid >> 4;   // row group: rows ty*8 .. ty*8+7

    float acc[8][4];
    #pragma unroll
    for (int i = 0; i < 8; ++i)
        #pragma unroll
        for (int j = 0; j < 4; ++j) acc[i][j] = 0.f;

    for (int kc = 0; kc < N_IN_CH; kc += KC) {
        #pragma unroll
        for (int it = 0; it < 8; ++it) {
            int f = it * 256 + tid;      // 0..2047
            int r = f >> 4;
            int kq = f & 15;
            int gr = row0 + r;
            float4 v = make_float4(0.f, 0.f, 0.f, 0.f);
            if (gr < nrows)
                v = *(const float4*)&X[(size_t)gr * N_IN_CH + kc + kq * 4];
            *(float4*)&Xs[r][kq * 4] = v;
        }
        #pragma unroll
        for (int it = 0; it < 4; ++it) {
            int f = it * 256 + tid;
            int k = f >> 4;
            int cq = f & 15;
            *(float4*)&Ws[k][cq * 4] =
                *(const float4*)&WT[(size_t)(kc + k) * N_OUT_CH + cq * 4];
        }
        __syncthreads();

        #pragma unroll
        for (int k4 = 0; k4 < KC; k4 += 4) {
            float4 wb[4];
            #pragma unroll
            for (int j = 0; j < 4; ++j)
                wb[j] = *(const float4*)&Ws[k4 + j][tx * 4];
            #pragma unroll
            for (int i = 0; i < 8; ++i) {
                float4 a = *(const float4*)&Xs[ty * 8 + i][k4];
                #pragma unroll
                for (int j = 0; j < 4; ++j) {
                    acc[i][j] = fmaf(a.x, ((const float*)&wb[0])[j],
                                fmaf(a.y, ((const float*)&wb[1])[j],
                                fmaf(a.z, ((const float*)&wb[2])[j],
                                fmaf(a.w, ((const float*)&wb[3])[j], acc[i][j]))));
                }
            }
        }
        __syncthreads();
    }

    #pragma unroll
    for (int i = 0; i < 8; ++i) {
        int gr = row0 + ty * 8 + i;
        if (gr < nrows) {
            float4 v = make_float4(acc[i][0], acc[i][1], acc[i][2], acc[i][3]);
            *(float4*)&Xp[(size_t)gr * N_OUT_CH + tx * 4] = v;
        }
    }
}

// --- CSR build phase ---
__global__ void hist_kernel(const int* __restrict__ rows, int* __restrict__ cnt, int nnz) {
    int e = blockIdx.x * blockDim.x + threadIdx.x;
    if (e < nnz) atomicAdd(&cnt[rows[e]], 1);
}

// Single-block in-place exclusive scan: counts[] -> starts[]
__global__ __launch_bounds__(NT_SCAN) void scan_kernel(int* __restrict__ c, int n) {
    __shared__ int part[NT_SCAN];
    const int t = threadIdx.x;
    const int chunk = (n + NT_SCAN - 1) / NT_SCAN;
    const int lo = t * chunk;
    const int hi = min(lo + chunk, n);

    int s = 0;
    for (int i = lo; i < hi; ++i) s += c[i];
    part[t] = s;
    __syncthreads();
    // Hillis-Steele inclusive scan over 1024 partials
    for (int d = 1; d < NT_SCAN; d <<= 1) {
        int v = 0;
        if (t >= d) v = part[t - d];
        __syncthreads();
        if (t >= d) part[t] += v;
        __syncthreads();
    }
    int run = (t == 0) ? 0 : part[t - 1];
    for (int i = lo; i < hi; ++i) {
        int tmp = c[i];
        c[i] = run;        // exclusive start
        run += tmp;
    }
}

// Scatter edges into row-sorted (col,val) pairs; mutates starts -> ends
__global__ void scatter_kernel(const int* __restrict__ rows, const int* __restrict__ cols,
        const float* __restrict__ vals, int* __restrict__ starts,
        int2* __restrict__ colval, int nnz) {
    int e = blockIdx.x * blockDim.x + threadIdx.x;
    if (e < nnz) {
        int r = rows[e];
        int pos = atomicAdd(&starts[r], 1);
        int2 cv;
        cv.x = cols[e];
        cv.y = __float_as_int(vals[e]);
        colval[pos] = cv;
    }
}

// --- Kernel 3 (CSR): one wave per row, 64 lanes = 64 channels, no atomics ---
// After scatter, ends[r] = end of row r; start of row r = ends[r-1] (0 for r=0).
__global__ __launch_bounds__(256) void spmm_csr_kernel(const int* __restrict__ ends,
        const int2* __restrict__ colval, const float* __restrict__ Xp,
        float* __restrict__ out, int nrows) {
    int t = blockIdx.x * blockDim.x + threadIdx.x;
    int row = t >> 6;
    int lane = t & 63;
    if (row >= nrows) return;
    int start = (row == 0) ? 0 : ends[row - 1];
    int end = ends[row];
    float acc = 0.f;
    for (int i = start; i < end; ++i) {
        int2 cv = colval[i];                       // wave-uniform broadcast
        acc += __int_as_float(cv.y) * Xp[(size_t)cv.x * N_OUT_CH + lane];
    }
    out[(size_t)row * N_OUT_CH + lane] = acc;
}

// --- Fallback atomic SpMM (if ws too small) ---
__global__ __launch_bounds__(256) void spmm_atomic_kernel(const int* __restrict__ rows,
        const int* __restrict__ cols, const float* __restrict__ vals,
        const float* __restrict__ Xp, float* __restrict__ out, int nnz) {
    int t = blockIdx.x * blockDim.x + threadIdx.x;
    int e = t >> 6;
    int c = t & 63;
    if (e < nnz) {
        atomicAdd(&out[(size_t)rows[e] * N_OUT_CH + c],
                  vals[e] * Xp[(size_t)cols[e] * N_OUT_CH + c]);
    }
}

extern "C" void kernel_launch(void* const* d_in, const int* in_sizes, int n_in,
                              void* d_out, int out_size, void* d_ws, size_t ws_size,
                              hipStream_t stream) {
    const float* X      = (const float*)d_in[2];
    const float* W      = (const float*)d_in[3];
    const int*   L_rows = (const int*)d_in[4];
    const int*   L_cols = (const int*)d_in[5];
    const float* L_vals = (const float*)d_in[6];
    float* out = (float*)d_out;

    const int nrows = in_sizes[2] / N_IN_CH;   // 100000
    const int nnz   = in_sizes[4];             // 1600000

    // workspace layout (all 8B-aligned)
    size_t off_wt = 0;
    size_t off_xp = 65536;                                    // 64 KB
    size_t off_st = off_xp + (size_t)nrows * N_OUT_CH * 4;    // Xp: 25.6 MB
    size_t off_cv = off_st + ((size_t)nrows * 4 + 7) / 8 * 8; // starts: 400 KB
    size_t need   = off_cv + (size_t)nnz * 8;                 // colval: 12.8 MB

    float* WT = (float*)((char*)d_ws + off_wt);
    float* Xp = (float*)((char*)d_ws + off_xp);

    wt_kernel<<<(N_OUT_CH * N_IN_CH + 255) / 256, 256, 0, stream>>>(W, WT);
    gemm_kernel<<<(nrows + TILE_R - 1) / TILE_R, 256, 0, stream>>>(X, WT, Xp, nrows);

    if (ws_size >= need) {
        int*  starts = (int*)((char*)d_ws + off_st);
        int2* colval = (int2*)((char*)d_ws + off_cv);

        hipMemsetAsync(starts, 0, (size_t)nrows * 4, stream);
        hist_kernel<<<(nnz + 255) / 256, 256, 0, stream>>>(L_rows, starts, nnz);
        scan_kernel<<<1, NT_SCAN, 0, stream>>>(starts, nrows);
        scatter_kernel<<<(nnz + 255) / 256, 256, 0, stream>>>(L_rows, L_cols, L_vals,
                                                              starts, colval, nnz);
        long long total = (long long)nrows * 64;
        spmm_csr_kernel<<<(int)((total + 255) / 256), 256, 0, stream>>>(starts, colval,
                                                                        Xp, out, nrows);
    } else {
        hipMemsetAsync(d_out, 0, (size_t)out_size * sizeof(float), stream);
        long long total = (long long)nnz * 64;
        spmm_atomic_kernel<<<(int)((total + 255) / 256), 256, 0, stream>>>(
            L_rows, L_cols, L_vals, Xp, out, nnz);
    }
}

// Round 3
// 563.118 us; speedup vs baseline: 1.2615x; 1.2615x over previous
//
#include <hip/hip_runtime.h>

#define N_IN_CH 256
#define N_OUT_CH 64
#define TILE_R 128
#define KC 64
#define SCAN_BS 1024

// --- Kernel 1: transpose W [64][256] -> WT [256][64] (k-major) ---
__global__ void wt_kernel(const float* __restrict__ W, float* __restrict__ WT) {
    int idx = blockIdx.x * blockDim.x + threadIdx.x;
    if (idx < N_OUT_CH * N_IN_CH) {
        int o = idx >> 8;      // / 256
        int k = idx & 255;
        WT[k * N_OUT_CH + o] = W[idx];
    }
}

// --- Kernel 2: Xp = X @ W^T, fp32, LDS-tiled, 8x4 register tile ---
__global__ __launch_bounds__(256) void gemm_kernel(const float* __restrict__ X,
        const float* __restrict__ WT, float* __restrict__ Xp, int nrows) {
    __shared__ float Xs[TILE_R][KC + 4];
    __shared__ float Ws[KC][N_OUT_CH];

    const int tid = threadIdx.x;
    const int row0 = blockIdx.x * TILE_R;
    const int tx = tid & 15;
    const int ty = tid >> 4;

    float acc[8][4];
    #pragma unroll
    for (int i = 0; i < 8; ++i)
        #pragma unroll
        for (int j = 0; j < 4; ++j) acc[i][j] = 0.f;

    for (int kc = 0; kc < N_IN_CH; kc += KC) {
        #pragma unroll
        for (int it = 0; it < 8; ++it) {
            int f = it * 256 + tid;
            int r = f >> 4;
            int kq = f & 15;
            int gr = row0 + r;
            float4 v = make_float4(0.f, 0.f, 0.f, 0.f);
            if (gr < nrows)
                v = *(const float4*)&X[(size_t)gr * N_IN_CH + kc + kq * 4];
            *(float4*)&Xs[r][kq * 4] = v;
        }
        #pragma unroll
        for (int it = 0; it < 4; ++it) {
            int f = it * 256 + tid;
            int k = f >> 4;
            int cq = f & 15;
            *(float4*)&Ws[k][cq * 4] =
                *(const float4*)&WT[(size_t)(kc + k) * N_OUT_CH + cq * 4];
        }
        __syncthreads();

        #pragma unroll
        for (int k4 = 0; k4 < KC; k4 += 4) {
            float4 wb[4];
            #pragma unroll
            for (int j = 0; j < 4; ++j)
                wb[j] = *(const float4*)&Ws[k4 + j][tx * 4];
            #pragma unroll
            for (int i = 0; i < 8; ++i) {
                float4 a = *(const float4*)&Xs[ty * 8 + i][k4];
                #pragma unroll
                for (int j = 0; j < 4; ++j) {
                    acc[i][j] = fmaf(a.x, ((const float*)&wb[0])[j],
                                fmaf(a.y, ((const float*)&wb[1])[j],
                                fmaf(a.z, ((const float*)&wb[2])[j],
                                fmaf(a.w, ((const float*)&wb[3])[j], acc[i][j]))));
                }
            }
        }
        __syncthreads();
    }

    #pragma unroll
    for (int i = 0; i < 8; ++i) {
        int gr = row0 + ty * 8 + i;
        if (gr < nrows) {
            float4 v = make_float4(acc[i][0], acc[i][1], acc[i][2], acc[i][3]);
            *(float4*)&Xp[(size_t)gr * N_OUT_CH + tx * 4] = v;
        }
    }
}

// --- CSR build phase ---
__global__ void hist_kernel(const int* __restrict__ rows, int* __restrict__ cnt, int nnz) {
    int e = blockIdx.x * blockDim.x + threadIdx.x;
    if (e < nnz) atomicAdd(&cnt[rows[e]], 1);
}

// Parallel exclusive scan, 3 phases, SCAN_BS elements per block.
__global__ __launch_bounds__(SCAN_BS) void scan1_kernel(const int* __restrict__ c,
        int* __restrict__ bsum, int n) {
    __shared__ int sd[SCAN_BS / 64];
    int i = blockIdx.x * SCAN_BS + threadIdx.x;
    int v = (i < n) ? c[i] : 0;
    #pragma unroll
    for (int d = 32; d > 0; d >>= 1) v += __shfl_down(v, d, 64);
    if ((threadIdx.x & 63) == 0) sd[threadIdx.x >> 6] = v;
    __syncthreads();
    if (threadIdx.x < SCAN_BS / 64) {
        int s = sd[threadIdx.x];
        #pragma unroll
        for (int d = SCAN_BS / 128; d > 0; d >>= 1) s += __shfl_down(s, d, 64);
        if (threadIdx.x == 0) bsum[blockIdx.x] = s;
    }
}

__global__ __launch_bounds__(SCAN_BS) void scan2_kernel(int* __restrict__ bsum, int nb) {
    __shared__ int sh[SCAN_BS];
    int t = threadIdx.x;
    int v = (t < nb) ? bsum[t] : 0;
    sh[t] = v;
    __syncthreads();
    for (int d = 1; d < SCAN_BS; d <<= 1) {
        int u = (t >= d) ? sh[t - d] : 0;
        __syncthreads();
        sh[t] += u;
        __syncthreads();
    }
    if (t < nb) bsum[t] = sh[t] - v;   // exclusive
}

__global__ __launch_bounds__(SCAN_BS) void scan3_kernel(int* __restrict__ c,
        const int* __restrict__ bsum, int n) {
    __shared__ int sh[SCAN_BS];
    int i = blockIdx.x * SCAN_BS + threadIdx.x;
    int t = threadIdx.x;
    int v = (i < n) ? c[i] : 0;
    sh[t] = v;
    __syncthreads();
    for (int d = 1; d < SCAN_BS; d <<= 1) {
        int u = (t >= d) ? sh[t - d] : 0;
        __syncthreads();
        sh[t] += u;
        __syncthreads();
    }
    if (i < n) c[i] = sh[t] - v + bsum[blockIdx.x];
}

// Scatter edges into row-sorted (col,val) pairs; mutates starts -> ends
__global__ void scatter_kernel(const int* __restrict__ rows, const int* __restrict__ cols,
        const float* __restrict__ vals, int* __restrict__ starts,
        int2* __restrict__ colval, int nnz) {
    int e = blockIdx.x * blockDim.x + threadIdx.x;
    if (e < nnz) {
        int r = rows[e];
        int pos = atomicAdd(&starts[r], 1);
        int2 cv;
        cv.x = cols[e];
        cv.y = __float_as_int(vals[e]);
        colval[pos] = cv;
    }
}

// --- Kernel 3 (CSR): one wave per row, 64 lanes = 64 channels, no atomics ---
__global__ __launch_bounds__(256) void spmm_csr_kernel(const int* __restrict__ ends,
        const int2* __restrict__ colval, const float* __restrict__ Xp,
        float* __restrict__ out, int nrows) {
    int t = blockIdx.x * blockDim.x + threadIdx.x;
    int row = t >> 6;
    int lane = t & 63;
    if (row >= nrows) return;
    int start = (row == 0) ? 0 : ends[row - 1];
    int end = ends[row];
    float acc = 0.f;
    for (int i = start; i < end; ++i) {
        int2 cv = colval[i];
        acc += __int_as_float(cv.y) * Xp[(size_t)cv.x * N_OUT_CH + lane];
    }
    out[(size_t)row * N_OUT_CH + lane] = acc;
}

// --- Fallback atomic SpMM (if ws too small) ---
__global__ __launch_bounds__(256) void spmm_atomic_kernel(const int* __restrict__ rows,
        const int* __restrict__ cols, const float* __restrict__ vals,
        const float* __restrict__ Xp, float* __restrict__ out, int nnz) {
    int t = blockIdx.x * blockDim.x + threadIdx.x;
    int e = t >> 6;
    int c = t & 63;
    if (e < nnz) {
        atomicAdd(&out[(size_t)rows[e] * N_OUT_CH + c],
                  vals[e] * Xp[(size_t)cols[e] * N_OUT_CH + c]);
    }
}

extern "C" void kernel_launch(void* const* d_in, const int* in_sizes, int n_in,
                              void* d_out, int out_size, void* d_ws, size_t ws_size,
                              hipStream_t stream) {
    const float* X      = (const float*)d_in[2];
    const float* W      = (const float*)d_in[3];
    const int*   L_rows = (const int*)d_in[4];
    const int*   L_cols = (const int*)d_in[5];
    const float* L_vals = (const float*)d_in[6];
    float* out = (float*)d_out;

    const int nrows = in_sizes[2] / N_IN_CH;   // 100000
    const int nnz   = in_sizes[4];             // 1600000

    const int nb_scan = (nrows + SCAN_BS - 1) / SCAN_BS;   // 98

    // workspace layout (all 8B-aligned)
    size_t off_wt = 0;
    size_t off_xp = 65536;                                    // 64 KB
    size_t off_st = off_xp + (size_t)nrows * N_OUT_CH * 4;    // Xp: 25.6 MB
    size_t off_bs = off_st + ((size_t)nrows * 4 + 7) / 8 * 8; // starts: 400 KB
    size_t off_cv = off_bs + ((size_t)nb_scan * 4 + 7) / 8 * 8;
    size_t need   = off_cv + (size_t)nnz * 8;                 // colval: 12.8 MB

    float* WT = (float*)((char*)d_ws + off_wt);
    float* Xp = (float*)((char*)d_ws + off_xp);

    wt_kernel<<<(N_OUT_CH * N_IN_CH + 255) / 256, 256, 0, stream>>>(W, WT);
    gemm_kernel<<<(nrows + TILE_R - 1) / TILE_R, 256, 0, stream>>>(X, WT, Xp, nrows);

    if (ws_size >= need) {
        int*  starts = (int*)((char*)d_ws + off_st);
        int*  bsum   = (int*)((char*)d_ws + off_bs);
        int2* colval = (int2*)((char*)d_ws + off_cv);

        hipMemsetAsync(starts, 0, (size_t)nrows * 4, stream);
        hist_kernel<<<(nnz + 255) / 256, 256, 0, stream>>>(L_rows, starts, nnz);
        scan1_kernel<<<nb_scan, SCAN_BS, 0, stream>>>(starts, bsum, nrows);
        scan2_kernel<<<1, SCAN_BS, 0, stream>>>(bsum, nb_scan);
        scan3_kernel<<<nb_scan, SCAN_BS, 0, stream>>>(starts, bsum, nrows);
        scatter_kernel<<<(nnz + 255) / 256, 256, 0, stream>>>(L_rows, L_cols, L_vals,
                                                              starts, colval, nnz);
        long long total = (long long)nrows * 64;
        spmm_csr_kernel<<<(int)((total + 255) / 256), 256, 0, stream>>>(starts, colval,
                                                                        Xp, out, nrows);
    } else {
        hipMemsetAsync(d_out, 0, (size_t)out_size * sizeof(float), stream);
        long long total = (long long)nnz * 64;
        spmm_atomic_kernel<<<(int)((total + 255) / 256), 256, 0, stream>>>(
            L_rows, L_cols, L_vals, Xp, out, nnz);
    }
}

// Round 4
// 448.362 us; speedup vs baseline: 1.5844x; 1.2559x over previous
//
#include <hip/hip_runtime.h>

#define N_IN_CH 256
#define N_OUT_CH 64
#define SCAN_BS 1024
#define XPAD 264   // 256 + 8 ushort pad: row stride 528 B -> conflict-free b128

typedef __attribute__((ext_vector_type(8))) short short8;
typedef __attribute__((ext_vector_type(4))) float f32x4;

__device__ inline ushort f2bf(float f) {
    unsigned u = __float_as_uint(f);
    return (ushort)((u + 0x7FFFu + ((u >> 16) & 1u)) >> 16);   // RTNE
}
__device__ inline float bf2f(ushort u) {
    return __uint_as_float(((unsigned)u) << 16);
}

// --- Kernel 1: W [64][256] fp32 -> bf16 (already [n][k], no transpose) ---
__global__ void wbf_kernel(const float* __restrict__ W, ushort* __restrict__ Wbf) {
    int i = blockIdx.x * blockDim.x + threadIdx.x;
    if (i < N_OUT_CH * N_IN_CH) Wbf[i] = f2bf(W[i]);
}

// --- Kernel 2: Xp = X @ W^T via bf16 MFMA; 64 rows/block, K=256 in one shot ---
__global__ __launch_bounds__(256) void mfma_gemm_kernel(const float* __restrict__ X,
        const ushort* __restrict__ Wbf, ushort* __restrict__ Xp, int nrows) {
    __shared__ ushort Xs[64 * XPAD];
    __shared__ ushort Ws[64 * XPAD];

    const int tid = threadIdx.x;
    const int row0 = blockIdx.x * 64;

    // stage W: 64x256 bf16, 16 ushort4 per thread
    #pragma unroll
    for (int it = 0; it < 16; ++it) {
        int f = it * 256 + tid;          // 0..4095 ushort4 slots
        int n = f >> 6, c4 = f & 63;
        ushort4 v = *(const ushort4*)&Wbf[n * N_IN_CH + c4 * 4];
        *(ushort4*)&Ws[n * XPAD + c4 * 4] = v;
    }
    // stage X with fused fp32->bf16 convert: 64x256
    #pragma unroll
    for (int it = 0; it < 16; ++it) {
        int f = it * 256 + tid;
        int r = f >> 6, c4 = f & 63;
        int gr = row0 + r;
        float4 x = make_float4(0.f, 0.f, 0.f, 0.f);
        if (gr < nrows) x = *(const float4*)&X[(size_t)gr * N_IN_CH + c4 * 4];
        ushort4 u;
        u.x = f2bf(x.x); u.y = f2bf(x.y); u.z = f2bf(x.z); u.w = f2bf(x.w);
        *(ushort4*)&Xs[r * XPAD + c4 * 4] = u;
    }
    __syncthreads();

    const int wave = tid >> 6, lane = tid & 63;
    const int ml = lane & 15, quad = lane >> 4;

    // A-fragments: lane holds A[m=ml][k=kt*32+quad*8 .. +8], 16B contiguous
    const ushort* abase = &Xs[(wave * 16 + ml) * XPAD + quad * 8];
    short8 a[8];
    #pragma unroll
    for (int kt = 0; kt < 8; ++kt) a[kt] = *(const short8*)&abase[kt * 32];

    // B-fragments: lane holds B[k][n=ml] = W[n=ml][k], same k pattern
    const ushort* bbase = &Ws[ml * XPAD + quad * 8];

    #pragma unroll
    for (int nt = 0; nt < 4; ++nt) {
        f32x4 acc = {0.f, 0.f, 0.f, 0.f};
        #pragma unroll
        for (int kt = 0; kt < 8; ++kt) {
            short8 b = *(const short8*)&bbase[nt * 16 * XPAD + kt * 32];
            acc = __builtin_amdgcn_mfma_f32_16x16x32_bf16(a[kt], b, acc, 0, 0, 0);
        }
        // C/D: col = lane&15 (n within tile), row = quad*4+reg (m within tile)
        #pragma unroll
        for (int reg = 0; reg < 4; ++reg) {
            int gr = row0 + wave * 16 + quad * 4 + reg;
            if (gr < nrows)
                Xp[(size_t)gr * N_OUT_CH + nt * 16 + ml] = f2bf(acc[reg]);
        }
    }
}

// --- CSR build phase ---
__global__ void hist_kernel(const int* __restrict__ rows, int* __restrict__ cnt, int nnz) {
    int e = blockIdx.x * blockDim.x + threadIdx.x;
    if (e < nnz) atomicAdd(&cnt[rows[e]], 1);
}

__global__ __launch_bounds__(SCAN_BS) void scan1_kernel(const int* __restrict__ c,
        int* __restrict__ bsum, int n) {
    __shared__ int sd[SCAN_BS / 64];
    int i = blockIdx.x * SCAN_BS + threadIdx.x;
    int v = (i < n) ? c[i] : 0;
    #pragma unroll
    for (int d = 32; d > 0; d >>= 1) v += __shfl_down(v, d, 64);
    if ((threadIdx.x & 63) == 0) sd[threadIdx.x >> 6] = v;
    __syncthreads();
    if (threadIdx.x < SCAN_BS / 64) {
        int s = sd[threadIdx.x];
        #pragma unroll
        for (int d = SCAN_BS / 128; d > 0; d >>= 1) s += __shfl_down(s, d, 64);
        if (threadIdx.x == 0) bsum[blockIdx.x] = s;
    }
}

__global__ __launch_bounds__(SCAN_BS) void scan2_kernel(int* __restrict__ bsum, int nb) {
    __shared__ int sh[SCAN_BS];
    int t = threadIdx.x;
    int v = (t < nb) ? bsum[t] : 0;
    sh[t] = v;
    __syncthreads();
    for (int d = 1; d < SCAN_BS; d <<= 1) {
        int u = (t >= d) ? sh[t - d] : 0;
        __syncthreads();
        sh[t] += u;
        __syncthreads();
    }
    if (t < nb) bsum[t] = sh[t] - v;   // exclusive
}

__global__ __launch_bounds__(SCAN_BS) void scan3_kernel(int* __restrict__ c,
        const int* __restrict__ bsum, int n) {
    __shared__ int sh[SCAN_BS];
    int i = blockIdx.x * SCAN_BS + threadIdx.x;
    int t = threadIdx.x;
    int v = (i < n) ? c[i] : 0;
    sh[t] = v;
    __syncthreads();
    for (int d = 1; d < SCAN_BS; d <<= 1) {
        int u = (t >= d) ? sh[t - d] : 0;
        __syncthreads();
        sh[t] += u;
        __syncthreads();
    }
    if (i < n) c[i] = sh[t] - v + bsum[blockIdx.x];
}

__global__ void scatter_kernel(const int* __restrict__ rows, const int* __restrict__ cols,
        const float* __restrict__ vals, int* __restrict__ starts,
        int2* __restrict__ colval, int nnz) {
    int e = blockIdx.x * blockDim.x + threadIdx.x;
    if (e < nnz) {
        int r = rows[e];
        int pos = atomicAdd(&starts[r], 1);
        int2 cv;
        cv.x = cols[e];
        cv.y = __float_as_int(vals[e]);
        colval[pos] = cv;
    }
}

// --- Kernel 3: CSR SpMM, bf16 gathers, unroll-4 for MLP ---
__global__ __launch_bounds__(256) void spmm_csr_kernel(const int* __restrict__ ends,
        const int2* __restrict__ colval, const ushort* __restrict__ Xp,
        float* __restrict__ out, int nrows) {
    int t = blockIdx.x * blockDim.x + threadIdx.x;
    int row = t >> 6;
    int lane = t & 63;
    if (row >= nrows) return;
    int start = (row == 0) ? 0 : ends[row - 1];
    int end = ends[row];
    float a0 = 0.f, a1 = 0.f, a2 = 0.f, a3 = 0.f;
    int i = start;
    for (; i + 4 <= end; i += 4) {
        int2 c0 = colval[i], c1 = colval[i + 1], c2 = colval[i + 2], c3 = colval[i + 3];
        float x0 = bf2f(Xp[(size_t)c0.x * N_OUT_CH + lane]);
        float x1 = bf2f(Xp[(size_t)c1.x * N_OUT_CH + lane]);
        float x2 = bf2f(Xp[(size_t)c2.x * N_OUT_CH + lane]);
        float x3 = bf2f(Xp[(size_t)c3.x * N_OUT_CH + lane]);
        a0 += __int_as_float(c0.y) * x0;
        a1 += __int_as_float(c1.y) * x1;
        a2 += __int_as_float(c2.y) * x2;
        a3 += __int_as_float(c3.y) * x3;
    }
    for (; i < end; ++i) {
        int2 cv = colval[i];
        a0 += __int_as_float(cv.y) * bf2f(Xp[(size_t)cv.x * N_OUT_CH + lane]);
    }
    out[(size_t)row * N_OUT_CH + lane] = (a0 + a1) + (a2 + a3);
}

// --- Fallback atomic SpMM (ws too small — not expected) ---
__global__ __launch_bounds__(256) void spmm_atomic_kernel(const int* __restrict__ rows,
        const int* __restrict__ cols, const float* __restrict__ vals,
        const ushort* __restrict__ Xp, float* __restrict__ out, int nnz) {
    int t = blockIdx.x * blockDim.x + threadIdx.x;
    int e = t >> 6;
    int c = t & 63;
    if (e < nnz) {
        atomicAdd(&out[(size_t)rows[e] * N_OUT_CH + c],
                  vals[e] * bf2f(Xp[(size_t)cols[e] * N_OUT_CH + c]));
    }
}

extern "C" void kernel_launch(void* const* d_in, const int* in_sizes, int n_in,
                              void* d_out, int out_size, void* d_ws, size_t ws_size,
                              hipStream_t stream) {
    const float* X      = (const float*)d_in[2];
    const float* W      = (const float*)d_in[3];
    const int*   L_rows = (const int*)d_in[4];
    const int*   L_cols = (const int*)d_in[5];
    const float* L_vals = (const float*)d_in[6];
    float* out = (float*)d_out;

    const int nrows = in_sizes[2] / N_IN_CH;   // 100000
    const int nnz   = in_sizes[4];             // 1600000

    const int nb_scan = (nrows + SCAN_BS - 1) / SCAN_BS;

    // workspace layout (8B-aligned)
    size_t off_wbf = 0;                                          // 32 KB
    size_t off_xp  = 65536;
    size_t off_st  = off_xp + (size_t)nrows * N_OUT_CH * 2;      // Xp bf16: 12.8 MB
    size_t off_bs  = off_st + ((size_t)nrows * 4 + 7) / 8 * 8;   // starts: 400 KB
    size_t off_cv  = off_bs + ((size_t)nb_scan * 4 + 7) / 8 * 8;
    size_t need    = off_cv + (size_t)nnz * 8;                   // colval: 12.8 MB

    ushort* Wbf = (ushort*)((char*)d_ws + off_wbf);
    ushort* Xp  = (ushort*)((char*)d_ws + off_xp);

    wbf_kernel<<<(N_OUT_CH * N_IN_CH + 255) / 256, 256, 0, stream>>>(W, Wbf);
    mfma_gemm_kernel<<<(nrows + 63) / 64, 256, 0, stream>>>(X, Wbf, Xp, nrows);

    if (ws_size >= need) {
        int*  starts = (int*)((char*)d_ws + off_st);
        int*  bsum   = (int*)((char*)d_ws + off_bs);
        int2* colval = (int2*)((char*)d_ws + off_cv);

        hipMemsetAsync(starts, 0, (size_t)nrows * 4, stream);
        hist_kernel<<<(nnz + 255) / 256, 256, 0, stream>>>(L_rows, starts, nnz);
        scan1_kernel<<<nb_scan, SCAN_BS, 0, stream>>>(starts, bsum, nrows);
        scan2_kernel<<<1, SCAN_BS, 0, stream>>>(bsum, nb_scan);
        scan3_kernel<<<nb_scan, SCAN_BS, 0, stream>>>(starts, bsum, nrows);
        scatter_kernel<<<(nnz + 255) / 256, 256, 0, stream>>>(L_rows, L_cols, L_vals,
                                                              starts, colval, nnz);
        long long total = (long long)nrows * 64;
        spmm_csr_kernel<<<(int)((total + 255) / 256), 256, 0, stream>>>(starts, colval,
                                                                        Xp, out, nrows);
    } else {
        hipMemsetAsync(d_out, 0, (size_t)out_size * sizeof(float), stream);
        long long total = (long long)nnz * 64;
        spmm_atomic_kernel<<<(int)((total + 255) / 256), 256, 0, stream>>>(
            L_rows, L_cols, L_vals, Xp, out, nnz);
    }
}